// Round 2
// baseline (247.205 us; speedup 1.0000x reference)
//
#include <hip/hip_runtime.h>
#include <cfloat>

constexpr int B_ = 256, N_ = 16, M_ = 128, V_ = 64, H_ = 256, K_ = 8, NP1 = 17;
constexpr int KO = K_ * NP1;     // 136 outputs per batch
constexpr int TYPES_ = 12;

__global__ __launch_bounds__(256) void fused_template_kernel(
    const float* __restrict__ decodings,    // [B,N,M,V]
    const int*   __restrict__ target_types, // [B]
    const int*   __restrict__ spans,        // [B]
    const float* __restrict__ type_emb,     // [21,H]
    const float* __restrict__ W_sem,        // [SPANS,TYPES,H,KO]
    const float* __restrict__ b_sem,        // [SPANS,TYPES,KO]
    const float* __restrict__ gumbel,       // [B,K,NP1]
    float* __restrict__ out_d,              // [B,M,V]
    float* __restrict__ out_v)              // [B,40,3,V]
{
    const int b = blockIdx.x;
    const int t = threadIdx.x;

    __shared__ float te[H_];
    __shared__ float score[KO];
    __shared__ int   sel[K_];
    __shared__ int   wave_hi[2];

    const int tt = target_types[b];
    const int sp = spans[b];

    if (tt == 20) {
        // fixed start template: k==0 picks choice 1 (decoding 0), rest pick pad (0)
        if (t < K_) sel[t] = (t == 0) ? 1 : 0;
    } else {
        te[t] = type_emb[tt * H_ + t];
        __syncthreads();
        const int row = (sp - 2) * TYPES_ + (tt - 9);
        if (t < KO) {
            const float* W = W_sem + (size_t)row * H_ * KO + t;
            float acc = b_sem[row * KO + t];
            #pragma unroll 8
            for (int h = 0; h < H_; ++h)
                acc = fmaf(te[h], W[(size_t)h * KO], acc);
            const int n = t % NP1;                  // position within span dim
            const float g = gumbel[b * KO + t];
            // argmax(log_softmax(logits)+g) == argmax(logits+g) over valid n
            score[t] = (n <= sp) ? (acc + g) : -FLT_MAX;
        }
        __syncthreads();
        if (t < K_) {
            float bv = score[t * NP1];
            int bi = 0;
            for (int n = 1; n < NP1; ++n) {        // first-max (strict >) like jnp.argmax
                float v = score[t * NP1 + n];
                if (v > bv) { bv = v; bi = n; }
            }
            sel[t] = bi;
        }
    }
    __syncthreads();

    // ---- sequential template concatenation (uniform control flow per block) ----
    int idx = 0;
    for (int k = 0; k < K_; ++k) {
        if (idx >= M_) break;                      // olen would clip to 0 anyway
        const int s = sel[k];
        if (s == 0) continue;                      // pad template: olen == 0
        const float* seq = decodings + ((size_t)b * N_ + (s - 1)) * (M_ * V_);

        // per-position token = argmax over V (first-max); nonpad iff token != 0
        int nonpad = 0;
        if (t < M_) {
            const float4* p = reinterpret_cast<const float4*>(seq + t * V_);
            float bv = -FLT_MAX; int bi = 0;
            #pragma unroll
            for (int q = 0; q < V_ / 4; ++q) {
                float4 x = p[q];
                if (x.x > bv) { bv = x.x; bi = 4 * q + 0; }
                if (x.y > bv) { bv = x.y; bi = 4 * q + 1; }
                if (x.z > bv) { bv = x.z; bi = 4 * q + 2; }
                if (x.w > bv) { bv = x.w; bi = 4 * q + 3; }
            }
            nonpad = (bi != 0);
        }
        // olen = (highest nonpad position)+1 via per-wave ballot (positions 0..127 = waves 0,1)
        const unsigned long long mask = __ballot(nonpad);
        if ((t & 63) == 0 && (t >> 6) < 2)
            wave_hi[t >> 6] = mask ? (63 - __clzll(mask)) : -1;
        __syncthreads();
        int olen = (wave_hi[1] >= 0) ? (wave_hi[1] + 65) : (wave_hi[0] + 1);
        olen = min(olen, M_ - idx);

        // cooperative copy of olen rows (olen*16 float4s)
        const int cnt4 = olen * (V_ / 4);
        const float4* src4 = reinterpret_cast<const float4*>(seq);
        float4* dst4 = reinterpret_cast<float4*>(out_d + ((size_t)b * M_ + idx) * V_);
        for (int i = t; i < cnt4; i += 256) dst4[i] = src4[i];
        idx += olen;
        __syncthreads();                           // protect wave_hi reuse next iter
    }

    // ---- zero tail of new_d and all of new_v (harness poisons d_out) ----
    const float4 z = make_float4(0.f, 0.f, 0.f, 0.f);
    float4* db = reinterpret_cast<float4*>(out_d + (size_t)b * M_ * V_);
    for (int i = idx * (V_ / 4) + t; i < M_ * (V_ / 4); i += 256) db[i] = z;
    float4* dv = reinterpret_cast<float4*>(out_v + (size_t)b * (40 * 3 * V_));
    for (int i = t; i < (40 * 3 * V_) / 4; i += 256) dv[i] = z;
}

extern "C" void kernel_launch(void* const* d_in, const int* in_sizes, int n_in,
                              void* d_out, int out_size, void* d_ws, size_t ws_size,
                              hipStream_t stream) {
    const float* decodings    = (const float*)d_in[0];
    // d_in[1] = variables: unused (new_v is all zeros)
    const int*   target_types = (const int*)d_in[2];
    const int*   spans        = (const int*)d_in[3];
    const float* type_emb     = (const float*)d_in[4];
    const float* W_sem        = (const float*)d_in[5];
    const float* b_sem        = (const float*)d_in[6];
    const float* gumbel       = (const float*)d_in[7];

    float* out_d = (float*)d_out;
    float* out_v = out_d + (size_t)B_ * M_ * V_;

    fused_template_kernel<<<dim3(B_), dim3(256), 0, stream>>>(
        decodings, target_types, spans, type_emb, W_sem, b_sem, gumbel, out_d, out_v);
}